// Round 8
// baseline (2115.797 us; speedup 1.0000x reference)
//
#include <hip/hip_runtime.h>
#include <hip/hip_bf16.h>
#include <cstdint>
#include <cstddef>

// ---------------------------------------------------------------------------
// Round 8: GEMM epilogue LDS shrunk to 32-row x 4-phase (16.9 KB total LDS ->
// 8 blocks/CU, launch_bounds(256,8)); silu via v_rcp_f32 in gemm + attn.
// Everything else identical to round 7.
// ---------------------------------------------------------------------------

#define BB   8
#define NNN  1024
#define DDD  1024
#define HHH  8
#define DVV  128
#define CCC  4096
#define TBK  128

typedef __bf16 bf8_t  __attribute__((ext_vector_type(8)));
typedef float  f4_t   __attribute__((ext_vector_type(4)));
typedef ushort us8_t  __attribute__((ext_vector_type(8)));

__device__ __forceinline__ float bf2f(ushort u) {
  union { uint i; float f; } v; v.i = ((uint)u) << 16; return v.f;
}
__device__ __forceinline__ ushort f2bf(float f) {
  __hip_bfloat16 h = __float2bfloat16(f);
  return *(ushort*)&h;
}
__device__ __forceinline__ float silu(float z) {
  // z * rcp(1+exp(-z)); v_rcp_f32 (~2.5e-7 rel err) instead of IEEE div.
  return z * __builtin_amdgcn_rcpf(1.f + __expf(-z));
}

// ---------------- block reduce (blockDim 256 or 1024) ----------------------
__device__ __forceinline__ float block_reduce_sum(float v, float* sm) {
#pragma unroll
  for (int o = 32; o > 0; o >>= 1) v += __shfl_down(v, o, 64);
  int lane = threadIdx.x & 63;
  int wid  = threadIdx.x >> 6;
  __syncthreads();
  if (lane == 0) sm[wid] = v;
  __syncthreads();
  int nw = blockDim.x >> 6;
  float r = (threadIdx.x < nw) ? sm[threadIdx.x] : 0.f;
#pragma unroll
  for (int o = 8; o > 0; o >>= 1) r += __shfl_down(r, o, 64);
  if (threadIdx.x == 0) sm[0] = r;
  __syncthreads();
  return sm[0];
}

// ---------------- len[b] ----------------------------------------------------
__global__ __launch_bounds__(1024) void len_k(const float* __restrict__ mask,
                                              int* __restrict__ lenp) {
  __shared__ float sm[16];
  int b = blockIdx.x;
  float m = mask[(size_t)b * NNN + threadIdx.x];
  float s = block_reduce_sum(m, sm);
  if (threadIdx.x == 0) lenp[b] = (int)(s + 0.5f);
}

// ---------------- all weight transposes in one launch -----------------------
__global__ __launch_bounds__(256) void wconv_all_k(const float* __restrict__ w_uvqk,
                                                   const float* __restrict__ w_o,
                                                   ushort* __restrict__ wuT,
                                                   ushort* __restrict__ woT) {
  __shared__ float t[32][33];
  int l = blockIdx.z;
  int k0 = blockIdx.x * 32;
  int by = blockIdx.y;
  const float* W; ushort* Wt; int Nn, n0;
  if (by < 128) {
    W = w_uvqk + (size_t)l * DDD * CCC; Wt = wuT + (size_t)l * CCC * DDD;
    Nn = CCC; n0 = by * 32;
  } else {
    W = w_o + (size_t)l * DDD * DDD; Wt = woT + (size_t)l * DDD * DDD;
    Nn = DDD; n0 = (by - 128) * 32;
  }
  int tx = threadIdx.x & 31, ty = threadIdx.x >> 5;
  for (int r = ty; r < 32; r += 8)
    t[r][tx] = W[(size_t)(k0 + r) * Nn + n0 + tx];
  __syncthreads();
  for (int r = ty; r < 32; r += 8)
    Wt[(size_t)(n0 + r) * 1024 + k0 + tx] = f2bf(t[tx][r]);
}

// ---------------- rab precompute -------------------------------------------
__global__ __launch_bounds__(256) void rab_k(const int* __restrict__ ts,
                                             const float* __restrict__ pos_w,
                                             const float* __restrict__ ts_w,
                                             const int* __restrict__ lenp,
                                             ushort* __restrict__ rabb) {
  int jt = blockIdx.x, it = blockIdx.y, b = blockIdx.z;
  if (jt > it) return;
  int len = lenp[b];
  if (it * 128 >= len || jt * 128 >= len) return;
  int j = jt * 128 + (threadIdx.x & 127);
  int half = threadIdx.x >> 7;
  int tsj = ts[(size_t)b * NNN + j];
  for (int rr = 0; rr < 64; ++rr) {
    int i = it * 128 + rr * 2 + half;
    int ii = i + 1; if (ii > NNN - 1) ii = NNN - 1;
    int tsi = ts[(size_t)b * NNN + ii];
    float af = fabsf((float)(tsi - tsj));
    af = fmaxf(af, 1.f);
    int bkt = (int)__log2f(af);
    bkt = min(max(bkt, 0), TBK);
    float rab = pos_w[i - j + NNN - 1] + ts_w[bkt];
    rabb[((size_t)b * NNN + i) * NNN + j] = f2bf(rab);
  }
}

// ---------------- LayerNorm. FIRST=1: also copy x -> xb. umat: bf16 u -------
template <int FIRST>
__global__ __launch_bounds__(256) void ln_k(const float* __restrict__ X,
                                            const float* __restrict__ g,
                                            const float* __restrict__ bsh,
                                            const ushort* __restrict__ umat,
                                            const int* __restrict__ lenp,
                                            float* __restrict__ xb,
                                            ushort* __restrict__ Y) {
  __shared__ float sm[16];
  size_t row = blockIdx.x;
  if (((int)row & 1023) >= lenp[row >> 10]) return;
  const float* xr = X + row * DDD;
  int d = threadIdx.x * 4;
  float4 xv = *(const float4*)(xr + d);
  if (FIRST) *(float4*)(xb + row * DDD + d) = xv;
  float s = xv.x + xv.y + xv.z + xv.w;
  s = block_reduce_sum(s, sm);
  float mu = s * (1.f / 1024.f);
  float d0 = xv.x - mu, d1 = xv.y - mu, d2 = xv.z - mu, d3 = xv.w - mu;
  float ss = d0 * d0 + d1 * d1 + d2 * d2 + d3 * d3;
  ss = block_reduce_sum(ss, sm);
  float rs = rsqrtf(ss * (1.f / 1024.f) + 1e-6f);
  float y0 = d0 * rs * g[d + 0] + bsh[d + 0];
  float y1 = d1 * rs * g[d + 1] + bsh[d + 1];
  float y2 = d2 * rs * g[d + 2] + bsh[d + 2];
  float y3 = d3 * rs * g[d + 3] + bsh[d + 3];
  if (umat != nullptr) {
    ushort4 uv = *(const ushort4*)(umat + row * 1024 + d);
    y0 *= bf2f(uv.x); y1 *= bf2f(uv.y); y2 *= bf2f(uv.z); y3 *= bf2f(uv.w);
  }
  ushort tmp[4] = { f2bf(y0), f2bf(y1), f2bf(y2), f2bf(y3) };
  *(uint2*)(Y + row * DDD + d) = *(uint2*)tmp;
}

// ---------------- bf16 MFMA GEMM, BK=32, 4-phase 32-row epilogue ------------
// MODE 1: C(fp32) += z + bias   (w_o GEMM, Nn=1024), full-line float4 RMW.
// MODE 2: uvqk split by 1024-col region:
//   region 0: u  -> U bf16 (stride 1024), silu
//   region 1: v  -> Vt[b,h,dv,n] bf16 transposed, silu
//   region 2/3: q,k -> Qk bf16 (stride 2048), silu
// LDS = max(staging 16384, eps 32x132x4 = 16896) = 16896 -> 8 blocks/CU.
template <int MODE>
__global__ __launch_bounds__(256, 8) void gemm_bf_k(const ushort* __restrict__ A,
                                                    const ushort* __restrict__ Bt,
                                                    const float* __restrict__ bias,
                                                    float* __restrict__ C,
                                                    ushort* __restrict__ U,
                                                    ushort* __restrict__ Qk,
                                                    ushort* __restrict__ Vt,
                                                    const int* __restrict__ lenp,
                                                    int K, int Nn) {
  __shared__ alignas(16) char smem[32 * 132 * 4];   // 16896 B
  ushort* As = (ushort*)smem;          // 128 x 32 (8192 B)
  ushort* Bs = As + 128 * 32;          // 128 x 32 (8192 B)
  float*  eps = (float*)smem;          // 32 x 132 epilogue scratch

  int m0 = blockIdx.y * 128, n0 = blockIdx.x * 128;
  if ((m0 & 1023) >= lenp[m0 >> 10]) return;
  int tid = threadIdx.x;
  int wave = tid >> 6, lane = tid & 63;
  int quad = lane >> 4, l16 = lane & 15;
  int wm = wave >> 1, wn = wave & 1;

  f4_t acc[4][4] = {};

  int r_l = tid >> 2;
  int p   = tid & 3;

  for (int k0 = 0; k0 < K; k0 += 32) {
    __syncthreads();
#pragma unroll
    for (int g = 0; g < 2; ++g) {
      int row = g * 64 + r_l;
      int q = (p - (row >> 1)) & 3;
      __builtin_amdgcn_global_load_lds(
          (const __attribute__((address_space(1))) void*)(A + (size_t)(m0 + row) * K + k0 + q * 8),
          (__attribute__((address_space(3))) void*)(As + (g * 64 + wave * 16) * 32),
          16, 0, 0);
      __builtin_amdgcn_global_load_lds(
          (const __attribute__((address_space(1))) void*)(Bt + (size_t)(n0 + row) * K + k0 + q * 8),
          (__attribute__((address_space(3))) void*)(Bs + (g * 64 + wave * 16) * 32),
          16, 0, 0);
    }
    __syncthreads();

    bf8_t af[4], bfr[4];
#pragma unroll
    for (int t = 0; t < 4; ++t) {
      int row = wm * 64 + t * 16 + l16;
      af[t] = *(const bf8_t*)&As[row * 32 + ((quad + (row >> 1)) & 3) * 8];
      int col = wn * 64 + t * 16 + l16;
      bfr[t] = *(const bf8_t*)&Bs[col * 32 + ((quad + (col >> 1)) & 3) * 8];
    }
#pragma unroll
    for (int i = 0; i < 4; ++i)
#pragma unroll
      for (int j = 0; j < 4; ++j)
        acc[i][j] = __builtin_amdgcn_mfma_f32_16x16x32_bf16(af[i], bfr[j],
                                                            acc[i][j], 0, 0, 0);
  }

  // ---- epilogue: 4 phases of 32 rows; LDS transpose then coalesced store
  int region = (MODE == 2) ? (n0 >> 10) : -1;
#pragma unroll
  for (int ph = 0; ph < 4; ++ph) {
    __syncthreads();   // frag reads / previous phase reads done
    if (wm == (ph >> 1)) {
      int ibase = (ph & 1) * 2;
#pragma unroll
      for (int ii = 0; ii < 2; ++ii)
#pragma unroll
        for (int j = 0; j < 4; ++j)
#pragma unroll
          for (int r = 0; r < 4; ++r)
            eps[(ii * 16 + quad * 4 + r) * 132 + wn * 64 + j * 16 + l16] =
                acc[ibase + ii][j][r];
    }
    __syncthreads();

    int mbase = m0 + ph * 32;
    if (MODE == 1 || region == 0 || region >= 2) {
      int row = tid >> 3;          // 0..31
      int c0 = (tid & 7) * 4;      // 0..28
      int gr = mbase + row;
      const float* er = eps + row * 132;
#pragma unroll
      for (int s = 0; s < 4; ++s) {
        int col = c0 + s * 32;
        float4 b4 = *(const float4*)(bias + n0 + col);
        float z0 = er[col + 0] + b4.x;
        float z1 = er[col + 1] + b4.y;
        float z2 = er[col + 2] + b4.z;
        float z3 = er[col + 3] + b4.w;
        if (MODE == 1) {
          float* cp = C + (size_t)gr * Nn + n0 + col;
          float4 c4 = *(const float4*)cp;
          c4.x += z0; c4.y += z1; c4.z += z2; c4.w += z3;
          *(float4*)cp = c4;
        } else {
          ushort4 pk;
          pk.x = f2bf(silu(z0)); pk.y = f2bf(silu(z1));
          pk.z = f2bf(silu(z2)); pk.w = f2bf(silu(z3));
          if (region == 0)
            *(ushort4*)(U + (size_t)gr * 1024 + n0 + col) = pk;
          else
            *(ushort4*)(Qk + (size_t)gr * 2048 + (n0 + col - 2048)) = pk;
        }
      }
    } else {
      // region 1: V -> Vt transposed. 32 rows this phase.
      int col = tid & 127;
      int half = tid >> 7;
      float bz = bias[n0 + col];
      int hb = (n0 >> 7) & 7;
      ushort* vrow = Vt + (((size_t)((m0 >> 10) * 8 + hb)) * 128 + col) * NNN +
                     (mbase & 1023) + half * 16;
#pragma unroll
      for (int g = 0; g < 2; ++g) {
        us8_t pk;
#pragma unroll
        for (int e = 0; e < 8; ++e) {
          int r = half * 16 + g * 8 + e;
          pk[e] = f2bf(silu(eps[r * 132 + col] + bz));
        }
        *(us8_t*)(vrow + g * 8) = pk;
      }
    }
  }
}

// ---------------- MFMA flash attention --------------------------------------
__global__ __launch_bounds__(256, 4) void attn_mfma_k(
    const ushort* __restrict__ qk, const ushort* __restrict__ vt,
    const ushort* __restrict__ rabb, const float* __restrict__ mask,
    const int* __restrict__ lenp, float* __restrict__ o) {
  __shared__ alignas(16) ushort Ks[64 * 128];   // 16 KB
  __shared__ alignas(16) ushort Vs[128 * 64];   // 16 KB
  __shared__ alignas(16) ushort Ps[64 * 64];    // 8 KB
  int h = blockIdx.y, b = blockIdx.z;
  int qt = ((int)blockIdx.x + (int)blockIdx.y + 2 * (int)blockIdx.z) & 15;
  int n0 = qt * 64;
  if (n0 >= lenp[b]) return;
  int tid = threadIdx.x, w = tid >> 6, lane = tid & 63;
  int quad = lane >> 4, l16 = lane & 15;

  const ushort* qg0 = qk + ((size_t)(b * NNN + n0)) * 2048 + h * 128;
#pragma unroll
  for (int t = 0; t < 4; ++t) {
    int lrow = w * 16 + t * 4 + (lane >> 4);
    int q = ((lane & 15) - lrow) & 15;
    __builtin_amdgcn_global_load_lds(
        (const __attribute__((address_space(1))) void*)(qg0 + (size_t)lrow * 2048 + q * 8),
        (__attribute__((address_space(3))) void*)(Ks + (w * 16 + t * 4) * 128),
        16, 0, 0);
  }
  __syncthreads();
  bf8_t qf[4];
  {
    int lr = w * 16 + l16;
#pragma unroll
    for (int kk = 0; kk < 4; ++kk)
      qf[kk] = *(const bf8_t*)&Ks[lr * 128 + (((kk * 4 + quad) + lr) & 15) * 8];
  }

  f4_t oacc[8] = {};
  const ushort* kg0 = qk + (size_t)b * NNN * 2048 + 1024 + h * 128;
  const ushort* vg0 = vt + (size_t)(b * 8 + h) * 128 * NNN;
  const ushort* rb0 = rabb + ((size_t)(b * NNN + n0 + w * 16 + quad * 4)) * NNN;
  const float* mk0 = mask + (size_t)b * NNN;
  int mtmax = qt + 1;

  for (int mt = 0; mt < mtmax; ++mt) {
    int m0 = mt * 64;
    __syncthreads();
#pragma unroll
    for (int t = 0; t < 4; ++t) {
      int lrow = w * 16 + t * 4 + (lane >> 4);
      int q = ((lane & 15) - lrow) & 15;
      __builtin_amdgcn_global_load_lds(
          (const __attribute__((address_space(1))) void*)(kg0 + (size_t)(m0 + lrow) * 2048 + q * 8),
          (__attribute__((address_space(3))) void*)(Ks + (w * 16 + t * 4) * 128),
          16, 0, 0);
    }
#pragma unroll
    for (int t = 0; t < 4; ++t) {
      int dv = w * 32 + t * 8 + (lane >> 3);
      int q = ((lane & 7) - dv) & 7;
      __builtin_amdgcn_global_load_lds(
          (const __attribute__((address_space(1))) void*)(vg0 + (size_t)dv * NNN + m0 + q * 8),
          (__attribute__((address_space(3))) void*)(Vs + (w * 32 + t * 8) * 64),
          16, 0, 0);
    }
    ushort rv[4][4];
#pragma unroll
    for (int tj = 0; tj < 4; ++tj)
#pragma unroll
      for (int r = 0; r < 4; ++r)
        rv[tj][r] = rb0[(size_t)r * NNN + m0 + tj * 16 + l16];
    __syncthreads();

    f4_t sacc[4] = {};
#pragma unroll
    for (int kk = 0; kk < 4; ++kk) {
      bf8_t kf[4];
#pragma unroll
      for (int tj = 0; tj < 4; ++tj) {
        int lr = tj * 16 + l16;
        kf[tj] = *(const bf8_t*)&Ks[lr * 128 + (((kk * 4 + quad) + lr) & 15) * 8];
      }
#pragma unroll
      for (int tj = 0; tj < 4; ++tj)
        sacc[tj] = __builtin_amdgcn_mfma_f32_16x16x32_bf16(qf[kk], kf[tj],
                                                           sacc[tj], 0, 0, 0);
    }

#pragma unroll
    for (int tj = 0; tj < 4; ++tj) {
      int m = tj * 16 + l16;
      int gj = m0 + m;
      float msc = mk0[gj] * (1.f / 1024.f);
#pragma unroll
      for (int r = 0; r < 4; ++r) {
        int q = w * 16 + quad * 4 + r;
        int gi = n0 + q;
        float z = sacc[tj][r] + bf2f(rv[tj][r]);
        float pp = silu(z) * msc;
        if (gj > gi) pp = 0.f;
        Ps[q * 64 + (((m >> 3) + q) & 7) * 8 + (m & 7)] = f2bf(pp);
      }
    }

#pragma unroll
    for (int kk = 0; kk < 2; ++kk) {
      bf8_t pf, vf[8];
      {
        int q = w * 16 + l16;
        pf = *(const bf8_t*)&Ps[q * 64 + (((kk * 4 + quad) + q) & 7) * 8];
      }
#pragma unroll
      for (int tj = 0; tj < 8; ++tj) {
        int dv = tj * 16 + l16;
        vf[tj] = *(const bf8_t*)&Vs[dv * 64 + (((kk * 4 + quad) + dv) & 7) * 8];
      }
#pragma unroll
      for (int tj = 0; tj < 8; ++tj)
        oacc[tj] = __builtin_amdgcn_mfma_f32_16x16x32_bf16(pf, vf[tj],
                                                           oacc[tj], 0, 0, 0);
    }
  }

#pragma unroll
  for (int tj = 0; tj < 8; ++tj) {
    int col = h * 128 + tj * 16 + l16;
#pragma unroll
    for (int r = 0; r < 4; ++r) {
      int gi = n0 + w * 16 + quad * 4 + r;
      o[((size_t)(b * NNN + gi)) * DDD + col] = oacc[tj][r];
    }
  }
}

// ---------------- pooling ---------------------------------------------------
__global__ __launch_bounds__(256) void row_stats_k(const float* __restrict__ xb,
                                                   const int* __restrict__ lenp,
                                                   float* __restrict__ invn) {
  __shared__ float sm[16];
  size_t row = blockIdx.x;
  if (((int)row & 1023) >= lenp[row >> 10]) return;
  int d = threadIdx.x * 4;
  float4 xv = *(const float4*)(xb + row * DDD + d);
  float ss = xv.x * xv.x + xv.y * xv.y + xv.z * xv.z + xv.w * xv.w;
  ss = block_reduce_sum(ss, sm);
  if (threadIdx.x == 0) invn[row] = 1.f / fmaxf(sqrtf(ss), 1e-12f);
}

__global__ __launch_bounds__(1024) void pool_partial_k(const float* __restrict__ xb,
                                                       const float* __restrict__ invn,
                                                       const int* __restrict__ lenp,
                                                       float* __restrict__ partial) {
  int b = blockIdx.x, c = blockIdx.y, d = threadIdx.x;
  int len = lenp[b];
  float s = 0.f;
  int nbeg = c * 64;
  int nend = min(nbeg + 64, len);
  for (int n = nbeg; n < nend; ++n) {
    size_t r = (size_t)b * NNN + n;
    s += xb[r * DDD + d] * invn[r];
  }
  partial[((size_t)b * 16 + c) * DDD + d] = s;
}

__global__ __launch_bounds__(1024) void pool_final_k(const float* __restrict__ xb,
                                                     const float* __restrict__ invn,
                                                     const float* __restrict__ partial,
                                                     const int* __restrict__ lenp,
                                                     float* __restrict__ out) {
  __shared__ float sm[16];
  int b = blockIdx.x, d = threadIdx.x;
  int len = lenp[b];
  float s = 0.f;
#pragma unroll
  for (int c = 0; c < 16; ++c) s += partial[((size_t)b * 16 + c) * DDD + d];
  float avg = s / (float)len;
  size_t lr = (size_t)b * NNN + (len - 1);
  float last = xb[lr * DDD + d] * invn[lr];
  float pooled = 0.5f * (last + avg);
  float ssq = block_reduce_sum(pooled * pooled, sm);
  out[(size_t)b * DDD + d] = pooled / fmaxf(sqrtf(ssq), 1e-12f);
}

// ---------------- launch ----------------------------------------------------
extern "C" void kernel_launch(void* const* d_in, const int* in_sizes, int n_in,
                              void* d_out, int out_size, void* d_ws, size_t ws_size,
                              hipStream_t stream) {
  const float* x      = (const float*)d_in[0];
  const int*   ts     = (const int*)d_in[1];
  const float* mask   = (const float*)d_in[2];
  const float* ln1_g  = (const float*)d_in[3];
  const float* ln1_b  = (const float*)d_in[4];
  const float* w_uvqk = (const float*)d_in[5];
  const float* b_uvqk = (const float*)d_in[6];
  const float* ln2_g  = (const float*)d_in[7];
  const float* ln2_b  = (const float*)d_in[8];
  const float* w_o    = (const float*)d_in[9];
  const float* b_o    = (const float*)d_in[10];
  const float* pos_w  = (const float*)d_in[11];
  const float* ts_w   = (const float*)d_in[12];
  float* out = (float*)d_out;

  float* ws = (float*)d_ws;
  const size_t SZ = (size_t)BB * NNN * DDD;            // 8M
  float* xb   = ws;                                     // 8M f
  float* buf1 = ws + SZ;                                // 8M f (o)
  ushort* ubuf = (ushort*)(ws + 2 * SZ);                // 8192x1024 bf16 (u)
  ushort* hbf = (ushort*)(ws + 3 * SZ);                 // 8M bf16
  ushort* wuT = hbf + SZ;                               // 2 x 4096x1024
  ushort* woT = wuT + 2 * (size_t)DDD * CCC;            // 2 x 1024x1024
  ushort* qkb = woT + 2 * (size_t)DDD * DDD;            // 8192x2048
  ushort* vtb = qkb + (size_t)BB * NNN * 2048;          // 64x128x1024
  ushort* rabb = vtb + (size_t)BB * HHH * DVV * NNN;    // 8x1024x1024
  float* invn = (float*)(rabb + (size_t)BB * NNN * NNN);
  float* partial = invn + (size_t)BB * NNN;
  int* lenp = (int*)(partial + (size_t)BB * 16 * DDD);

  len_k<<<BB, 1024, 0, stream>>>(mask, lenp);
  wconv_all_k<<<dim3(32, 160, 2), 256, 0, stream>>>(w_uvqk, w_o, wuT, woT);
  rab_k<<<dim3(8, 8, BB), 256, 0, stream>>>(ts, pos_w, ts_w, lenp, rabb);

  for (int l = 0; l < 2; ++l) {
    if (l == 0)
      ln_k<1><<<BB * NNN, 256, 0, stream>>>(x, ln1_g, ln1_b, nullptr,
                                            lenp, xb, hbf);
    else
      ln_k<0><<<BB * NNN, 256, 0, stream>>>(xb, ln1_g + l * DDD,
                                            ln1_b + l * DDD, nullptr,
                                            lenp, nullptr, hbf);
    gemm_bf_k<2><<<dim3(CCC / 128, BB * NNN / 128), 256, 0, stream>>>(
        hbf, wuT + (size_t)l * CCC * DDD, b_uvqk + (size_t)l * CCC,
        nullptr, ubuf, qkb, vtb, lenp, DDD, CCC);
    attn_mfma_k<<<dim3(NNN / 64, HHH, BB), 256, 0, stream>>>(
        qkb, vtb, rabb, mask, lenp, buf1);
    ln_k<0><<<BB * NNN, 256, 0, stream>>>(buf1, ln2_g + l * DDD,
                                          ln2_b + l * DDD, ubuf,
                                          lenp, nullptr, hbf);
    gemm_bf_k<1><<<dim3(DDD / 128, BB * NNN / 128), 256, 0, stream>>>(
        hbf, woT + (size_t)l * DDD * DDD, b_o + (size_t)l * DDD,
        xb, nullptr, nullptr, nullptr, lenp, DDD, DDD);
  }

  row_stats_k<<<BB * NNN, 256, 0, stream>>>(xb, lenp, invn);
  pool_partial_k<<<dim3(BB, 16), 1024, 0, stream>>>(xb, invn, lenp, partial);
  pool_final_k<<<BB, 1024, 0, stream>>>(xb, invn, partial, lenp, out);
}

// Round 10
// 645.671 us; speedup vs baseline: 3.2769x; 3.2769x over previous
//
#include <hip/hip_runtime.h>
#include <hip/hip_bf16.h>
#include <cstdint>
#include <cstddef>

// ---------------------------------------------------------------------------
// Round 10: r8's validated body (4-phase 32-row epilogue, 16.9 KB LDS,
// rcp-silu) with GEMM launch bounds reverted to plain (256) — the r7-validated
// spec (natural VGPR=64, no spill). r9's (256,4) failed the post-timing
// harness check; (256,8) spilled. Plain bounds passed the full harness in r7.
// ---------------------------------------------------------------------------

#define BB   8
#define NNN  1024
#define DDD  1024
#define HHH  8
#define DVV  128
#define CCC  4096
#define TBK  128

typedef __bf16 bf8_t  __attribute__((ext_vector_type(8)));
typedef float  f4_t   __attribute__((ext_vector_type(4)));
typedef ushort us8_t  __attribute__((ext_vector_type(8)));

__device__ __forceinline__ float bf2f(ushort u) {
  union { uint i; float f; } v; v.i = ((uint)u) << 16; return v.f;
}
__device__ __forceinline__ ushort f2bf(float f) {
  __hip_bfloat16 h = __float2bfloat16(f);
  return *(ushort*)&h;
}
__device__ __forceinline__ float silu(float z) {
  return z * __builtin_amdgcn_rcpf(1.f + __expf(-z));
}

// ---------------- block reduce (blockDim 256 or 1024) ----------------------
__device__ __forceinline__ float block_reduce_sum(float v, float* sm) {
#pragma unroll
  for (int o = 32; o > 0; o >>= 1) v += __shfl_down(v, o, 64);
  int lane = threadIdx.x & 63;
  int wid  = threadIdx.x >> 6;
  __syncthreads();
  if (lane == 0) sm[wid] = v;
  __syncthreads();
  int nw = blockDim.x >> 6;
  float r = (threadIdx.x < nw) ? sm[threadIdx.x] : 0.f;
#pragma unroll
  for (int o = 8; o > 0; o >>= 1) r += __shfl_down(r, o, 64);
  if (threadIdx.x == 0) sm[0] = r;
  __syncthreads();
  return sm[0];
}

// ---------------- len[b] ----------------------------------------------------
__global__ __launch_bounds__(1024) void len_k(const float* __restrict__ mask,
                                              int* __restrict__ lenp) {
  __shared__ float sm[16];
  int b = blockIdx.x;
  float m = mask[(size_t)b * NNN + threadIdx.x];
  float s = block_reduce_sum(m, sm);
  if (threadIdx.x == 0) lenp[b] = (int)(s + 0.5f);
}

// ---------------- all weight transposes in one launch -----------------------
__global__ __launch_bounds__(256) void wconv_all_k(const float* __restrict__ w_uvqk,
                                                   const float* __restrict__ w_o,
                                                   ushort* __restrict__ wuT,
                                                   ushort* __restrict__ woT) {
  __shared__ float t[32][33];
  int l = blockIdx.z;
  int k0 = blockIdx.x * 32;
  int by = blockIdx.y;
  const float* W; ushort* Wt; int Nn, n0;
  if (by < 128) {
    W = w_uvqk + (size_t)l * DDD * CCC; Wt = wuT + (size_t)l * CCC * DDD;
    Nn = CCC; n0 = by * 32;
  } else {
    W = w_o + (size_t)l * DDD * DDD; Wt = woT + (size_t)l * DDD * DDD;
    Nn = DDD; n0 = (by - 128) * 32;
  }
  int tx = threadIdx.x & 31, ty = threadIdx.x >> 5;
  for (int r = ty; r < 32; r += 8)
    t[r][tx] = W[(size_t)(k0 + r) * Nn + n0 + tx];
  __syncthreads();
  for (int r = ty; r < 32; r += 8)
    Wt[(size_t)(n0 + r) * 1024 + k0 + tx] = f2bf(t[tx][r]);
}

// ---------------- rab precompute -------------------------------------------
__global__ __launch_bounds__(256) void rab_k(const int* __restrict__ ts,
                                             const float* __restrict__ pos_w,
                                             const float* __restrict__ ts_w,
                                             const int* __restrict__ lenp,
                                             ushort* __restrict__ rabb) {
  int jt = blockIdx.x, it = blockIdx.y, b = blockIdx.z;
  if (jt > it) return;
  int len = lenp[b];
  if (it * 128 >= len || jt * 128 >= len) return;
  int j = jt * 128 + (threadIdx.x & 127);
  int half = threadIdx.x >> 7;
  int tsj = ts[(size_t)b * NNN + j];
  for (int rr = 0; rr < 64; ++rr) {
    int i = it * 128 + rr * 2 + half;
    int ii = i + 1; if (ii > NNN - 1) ii = NNN - 1;
    int tsi = ts[(size_t)b * NNN + ii];
    float af = fabsf((float)(tsi - tsj));
    af = fmaxf(af, 1.f);
    int bkt = (int)__log2f(af);
    bkt = min(max(bkt, 0), TBK);
    float rab = pos_w[i - j + NNN - 1] + ts_w[bkt];
    rabb[((size_t)b * NNN + i) * NNN + j] = f2bf(rab);
  }
}

// ---------------- LayerNorm. FIRST=1: also copy x -> xb. umat: bf16 u -------
template <int FIRST>
__global__ __launch_bounds__(256) void ln_k(const float* __restrict__ X,
                                            const float* __restrict__ g,
                                            const float* __restrict__ bsh,
                                            const ushort* __restrict__ umat,
                                            const int* __restrict__ lenp,
                                            float* __restrict__ xb,
                                            ushort* __restrict__ Y) {
  __shared__ float sm[16];
  size_t row = blockIdx.x;
  if (((int)row & 1023) >= lenp[row >> 10]) return;
  const float* xr = X + row * DDD;
  int d = threadIdx.x * 4;
  float4 xv = *(const float4*)(xr + d);
  if (FIRST) *(float4*)(xb + row * DDD + d) = xv;
  float s = xv.x + xv.y + xv.z + xv.w;
  s = block_reduce_sum(s, sm);
  float mu = s * (1.f / 1024.f);
  float d0 = xv.x - mu, d1 = xv.y - mu, d2 = xv.z - mu, d3 = xv.w - mu;
  float ss = d0 * d0 + d1 * d1 + d2 * d2 + d3 * d3;
  ss = block_reduce_sum(ss, sm);
  float rs = rsqrtf(ss * (1.f / 1024.f) + 1e-6f);
  float y0 = d0 * rs * g[d + 0] + bsh[d + 0];
  float y1 = d1 * rs * g[d + 1] + bsh[d + 1];
  float y2 = d2 * rs * g[d + 2] + bsh[d + 2];
  float y3 = d3 * rs * g[d + 3] + bsh[d + 3];
  if (umat != nullptr) {
    ushort4 uv = *(const ushort4*)(umat + row * 1024 + d);
    y0 *= bf2f(uv.x); y1 *= bf2f(uv.y); y2 *= bf2f(uv.z); y3 *= bf2f(uv.w);
  }
  ushort tmp[4] = { f2bf(y0), f2bf(y1), f2bf(y2), f2bf(y3) };
  *(uint2*)(Y + row * DDD + d) = *(uint2*)tmp;
}

// ---------------- bf16 MFMA GEMM, BK=32, 4-phase 32-row epilogue ------------
// MODE 1: C(fp32) += z + bias   (w_o GEMM, Nn=1024), full-line float4 RMW.
// MODE 2: uvqk split by 1024-col region:
//   region 0: u  -> U bf16 (stride 1024), silu
//   region 1: v  -> Vt[b,h,dv,n] bf16 transposed, silu
//   region 2/3: q,k -> Qk bf16 (stride 2048), silu
// LDS = max(staging 16384, eps 32x132x4 = 16896) = 16896.
template <int MODE>
__global__ __launch_bounds__(256) void gemm_bf_k(const ushort* __restrict__ A,
                                                 const ushort* __restrict__ Bt,
                                                 const float* __restrict__ bias,
                                                 float* __restrict__ C,
                                                 ushort* __restrict__ U,
                                                 ushort* __restrict__ Qk,
                                                 ushort* __restrict__ Vt,
                                                 const int* __restrict__ lenp,
                                                 int K, int Nn) {
  __shared__ alignas(16) char smem[32 * 132 * 4];   // 16896 B
  ushort* As = (ushort*)smem;          // 128 x 32 (8192 B)
  ushort* Bs = As + 128 * 32;          // 128 x 32 (8192 B)
  float*  eps = (float*)smem;          // 32 x 132 epilogue scratch

  int m0 = blockIdx.y * 128, n0 = blockIdx.x * 128;
  if ((m0 & 1023) >= lenp[m0 >> 10]) return;
  int tid = threadIdx.x;
  int wave = tid >> 6, lane = tid & 63;
  int quad = lane >> 4, l16 = lane & 15;
  int wm = wave >> 1, wn = wave & 1;

  f4_t acc[4][4] = {};

  int r_l = tid >> 2;
  int p   = tid & 3;

  for (int k0 = 0; k0 < K; k0 += 32) {
    __syncthreads();
#pragma unroll
    for (int g = 0; g < 2; ++g) {
      int row = g * 64 + r_l;
      int q = (p - (row >> 1)) & 3;
      __builtin_amdgcn_global_load_lds(
          (const __attribute__((address_space(1))) void*)(A + (size_t)(m0 + row) * K + k0 + q * 8),
          (__attribute__((address_space(3))) void*)(As + (g * 64 + wave * 16) * 32),
          16, 0, 0);
      __builtin_amdgcn_global_load_lds(
          (const __attribute__((address_space(1))) void*)(Bt + (size_t)(n0 + row) * K + k0 + q * 8),
          (__attribute__((address_space(3))) void*)(Bs + (g * 64 + wave * 16) * 32),
          16, 0, 0);
    }
    __syncthreads();

    bf8_t af[4], bfr[4];
#pragma unroll
    for (int t = 0; t < 4; ++t) {
      int row = wm * 64 + t * 16 + l16;
      af[t] = *(const bf8_t*)&As[row * 32 + ((quad + (row >> 1)) & 3) * 8];
      int col = wn * 64 + t * 16 + l16;
      bfr[t] = *(const bf8_t*)&Bs[col * 32 + ((quad + (col >> 1)) & 3) * 8];
    }
#pragma unroll
    for (int i = 0; i < 4; ++i)
#pragma unroll
      for (int j = 0; j < 4; ++j)
        acc[i][j] = __builtin_amdgcn_mfma_f32_16x16x32_bf16(af[i], bfr[j],
                                                            acc[i][j], 0, 0, 0);
  }

  // ---- epilogue: 4 phases of 32 rows; LDS transpose then coalesced store
  int region = (MODE == 2) ? (n0 >> 10) : -1;
#pragma unroll
  for (int ph = 0; ph < 4; ++ph) {
    __syncthreads();   // frag reads / previous phase reads done
    if (wm == (ph >> 1)) {
      int ibase = (ph & 1) * 2;
#pragma unroll
      for (int ii = 0; ii < 2; ++ii)
#pragma unroll
        for (int j = 0; j < 4; ++j)
#pragma unroll
          for (int r = 0; r < 4; ++r)
            eps[(ii * 16 + quad * 4 + r) * 132 + wn * 64 + j * 16 + l16] =
                acc[ibase + ii][j][r];
    }
    __syncthreads();

    int mbase = m0 + ph * 32;
    if (MODE == 1 || region == 0 || region >= 2) {
      int row = tid >> 3;          // 0..31
      int c0 = (tid & 7) * 4;      // 0..28
      int gr = mbase + row;
      const float* er = eps + row * 132;
#pragma unroll
      for (int s = 0; s < 4; ++s) {
        int col = c0 + s * 32;
        float4 b4 = *(const float4*)(bias + n0 + col);
        float z0 = er[col + 0] + b4.x;
        float z1 = er[col + 1] + b4.y;
        float z2 = er[col + 2] + b4.z;
        float z3 = er[col + 3] + b4.w;
        if (MODE == 1) {
          float* cp = C + (size_t)gr * Nn + n0 + col;
          float4 c4 = *(const float4*)cp;
          c4.x += z0; c4.y += z1; c4.z += z2; c4.w += z3;
          *(float4*)cp = c4;
        } else {
          ushort4 pk;
          pk.x = f2bf(silu(z0)); pk.y = f2bf(silu(z1));
          pk.z = f2bf(silu(z2)); pk.w = f2bf(silu(z3));
          if (region == 0)
            *(ushort4*)(U + (size_t)gr * 1024 + n0 + col) = pk;
          else
            *(ushort4*)(Qk + (size_t)gr * 2048 + (n0 + col - 2048)) = pk;
        }
      }
    } else {
      // region 1: V -> Vt transposed. 32 rows this phase.
      int col = tid & 127;
      int half = tid >> 7;
      float bz = bias[n0 + col];
      int hb = (n0 >> 7) & 7;
      ushort* vrow = Vt + (((size_t)((m0 >> 10) * 8 + hb)) * 128 + col) * NNN +
                     (mbase & 1023) + half * 16;
#pragma unroll
      for (int g = 0; g < 2; ++g) {
        us8_t pk;
#pragma unroll
        for (int e = 0; e < 8; ++e) {
          int r = half * 16 + g * 8 + e;
          pk[e] = f2bf(silu(eps[r * 132 + col] + bz));
        }
        *(us8_t*)(vrow + g * 8) = pk;
      }
    }
  }
}

// ---------------- MFMA flash attention --------------------------------------
__global__ __launch_bounds__(256, 4) void attn_mfma_k(
    const ushort* __restrict__ qk, const ushort* __restrict__ vt,
    const ushort* __restrict__ rabb, const float* __restrict__ mask,
    const int* __restrict__ lenp, float* __restrict__ o) {
  __shared__ alignas(16) ushort Ks[64 * 128];   // 16 KB
  __shared__ alignas(16) ushort Vs[128 * 64];   // 16 KB
  __shared__ alignas(16) ushort Ps[64 * 64];    // 8 KB
  int h = blockIdx.y, b = blockIdx.z;
  int qt = ((int)blockIdx.x + (int)blockIdx.y + 2 * (int)blockIdx.z) & 15;
  int n0 = qt * 64;
  if (n0 >= lenp[b]) return;
  int tid = threadIdx.x, w = tid >> 6, lane = tid & 63;
  int quad = lane >> 4, l16 = lane & 15;

  const ushort* qg0 = qk + ((size_t)(b * NNN + n0)) * 2048 + h * 128;
#pragma unroll
  for (int t = 0; t < 4; ++t) {
    int lrow = w * 16 + t * 4 + (lane >> 4);
    int q = ((lane & 15) - lrow) & 15;
    __builtin_amdgcn_global_load_lds(
        (const __attribute__((address_space(1))) void*)(qg0 + (size_t)lrow * 2048 + q * 8),
        (__attribute__((address_space(3))) void*)(Ks + (w * 16 + t * 4) * 128),
        16, 0, 0);
  }
  __syncthreads();
  bf8_t qf[4];
  {
    int lr = w * 16 + l16;
#pragma unroll
    for (int kk = 0; kk < 4; ++kk)
      qf[kk] = *(const bf8_t*)&Ks[lr * 128 + (((kk * 4 + quad) + lr) & 15) * 8];
  }

  f4_t oacc[8] = {};
  const ushort* kg0 = qk + (size_t)b * NNN * 2048 + 1024 + h * 128;
  const ushort* vg0 = vt + (size_t)(b * 8 + h) * 128 * NNN;
  const ushort* rb0 = rabb + ((size_t)(b * NNN + n0 + w * 16 + quad * 4)) * NNN;
  const float* mk0 = mask + (size_t)b * NNN;
  int mtmax = qt + 1;

  for (int mt = 0; mt < mtmax; ++mt) {
    int m0 = mt * 64;
    __syncthreads();
#pragma unroll
    for (int t = 0; t < 4; ++t) {
      int lrow = w * 16 + t * 4 + (lane >> 4);
      int q = ((lane & 15) - lrow) & 15;
      __builtin_amdgcn_global_load_lds(
          (const __attribute__((address_space(1))) void*)(kg0 + (size_t)(m0 + lrow) * 2048 + q * 8),
          (__attribute__((address_space(3))) void*)(Ks + (w * 16 + t * 4) * 128),
          16, 0, 0);
    }
#pragma unroll
    for (int t = 0; t < 4; ++t) {
      int dv = w * 32 + t * 8 + (lane >> 3);
      int q = ((lane & 7) - dv) & 7;
      __builtin_amdgcn_global_load_lds(
          (const __attribute__((address_space(1))) void*)(vg0 + (size_t)dv * NNN + m0 + q * 8),
          (__attribute__((address_space(3))) void*)(Vs + (w * 32 + t * 8) * 64),
          16, 0, 0);
    }
    ushort rv[4][4];
#pragma unroll
    for (int tj = 0; tj < 4; ++tj)
#pragma unroll
      for (int r = 0; r < 4; ++r)
        rv[tj][r] = rb0[(size_t)r * NNN + m0 + tj * 16 + l16];
    __syncthreads();

    f4_t sacc[4] = {};
#pragma unroll
    for (int kk = 0; kk < 4; ++kk) {
      bf8_t kf[4];
#pragma unroll
      for (int tj = 0; tj < 4; ++tj) {
        int lr = tj * 16 + l16;
        kf[tj] = *(const bf8_t*)&Ks[lr * 128 + (((kk * 4 + quad) + lr) & 15) * 8];
      }
#pragma unroll
      for (int tj = 0; tj < 4; ++tj)
        sacc[tj] = __builtin_amdgcn_mfma_f32_16x16x32_bf16(qf[kk], kf[tj],
                                                           sacc[tj], 0, 0, 0);
    }

#pragma unroll
    for (int tj = 0; tj < 4; ++tj) {
      int m = tj * 16 + l16;
      int gj = m0 + m;
      float msc = mk0[gj] * (1.f / 1024.f);
#pragma unroll
      for (int r = 0; r < 4; ++r) {
        int q = w * 16 + quad * 4 + r;
        int gi = n0 + q;
        float z = sacc[tj][r] + bf2f(rv[tj][r]);
        float pp = silu(z) * msc;
        if (gj > gi) pp = 0.f;
        Ps[q * 64 + (((m >> 3) + q) & 7) * 8 + (m & 7)] = f2bf(pp);
      }
    }

#pragma unroll
    for (int kk = 0; kk < 2; ++kk) {
      bf8_t pf, vf[8];
      {
        int q = w * 16 + l16;
        pf = *(const bf8_t*)&Ps[q * 64 + (((kk * 4 + quad) + q) & 7) * 8];
      }
#pragma unroll
      for (int tj = 0; tj < 8; ++tj) {
        int dv = tj * 16 + l16;
        vf[tj] = *(const bf8_t*)&Vs[dv * 64 + (((kk * 4 + quad) + dv) & 7) * 8];
      }
#pragma unroll
      for (int tj = 0; tj < 8; ++tj)
        oacc[tj] = __builtin_amdgcn_mfma_f32_16x16x32_bf16(pf, vf[tj],
                                                           oacc[tj], 0, 0, 0);
    }
  }

#pragma unroll
  for (int tj = 0; tj < 8; ++tj) {
    int col = h * 128 + tj * 16 + l16;
#pragma unroll
    for (int r = 0; r < 4; ++r) {
      int gi = n0 + w * 16 + quad * 4 + r;
      o[((size_t)(b * NNN + gi)) * DDD + col] = oacc[tj][r];
    }
  }
}

// ---------------- pooling ---------------------------------------------------
__global__ __launch_bounds__(256) void row_stats_k(const float* __restrict__ xb,
                                                   const int* __restrict__ lenp,
                                                   float* __restrict__ invn) {
  __shared__ float sm[16];
  size_t row = blockIdx.x;
  if (((int)row & 1023) >= lenp[row >> 10]) return;
  int d = threadIdx.x * 4;
  float4 xv = *(const float4*)(xb + row * DDD + d);
  float ss = xv.x * xv.x + xv.y * xv.y + xv.z * xv.z + xv.w * xv.w;
  ss = block_reduce_sum(ss, sm);
  if (threadIdx.x == 0) invn[row] = 1.f / fmaxf(sqrtf(ss), 1e-12f);
}

__global__ __launch_bounds__(1024) void pool_partial_k(const float* __restrict__ xb,
                                                       const float* __restrict__ invn,
                                                       const int* __restrict__ lenp,
                                                       float* __restrict__ partial) {
  int b = blockIdx.x, c = blockIdx.y, d = threadIdx.x;
  int len = lenp[b];
  float s = 0.f;
  int nbeg = c * 64;
  int nend = min(nbeg + 64, len);
  for (int n = nbeg; n < nend; ++n) {
    size_t r = (size_t)b * NNN + n;
    s += xb[r * DDD + d] * invn[r];
  }
  partial[((size_t)b * 16 + c) * DDD + d] = s;
}

__global__ __launch_bounds__(1024) void pool_final_k(const float* __restrict__ xb,
                                                     const float* __restrict__ invn,
                                                     const float* __restrict__ partial,
                                                     const int* __restrict__ lenp,
                                                     float* __restrict__ out) {
  __shared__ float sm[16];
  int b = blockIdx.x, d = threadIdx.x;
  int len = lenp[b];
  float s = 0.f;
#pragma unroll
  for (int c = 0; c < 16; ++c) s += partial[((size_t)b * 16 + c) * DDD + d];
  float avg = s / (float)len;
  size_t lr = (size_t)b * NNN + (len - 1);
  float last = xb[lr * DDD + d] * invn[lr];
  float pooled = 0.5f * (last + avg);
  float ssq = block_reduce_sum(pooled * pooled, sm);
  out[(size_t)b * DDD + d] = pooled / fmaxf(sqrtf(ssq), 1e-12f);
}

// ---------------- launch ----------------------------------------------------
extern "C" void kernel_launch(void* const* d_in, const int* in_sizes, int n_in,
                              void* d_out, int out_size, void* d_ws, size_t ws_size,
                              hipStream_t stream) {
  const float* x      = (const float*)d_in[0];
  const int*   ts     = (const int*)d_in[1];
  const float* mask   = (const float*)d_in[2];
  const float* ln1_g  = (const float*)d_in[3];
  const float* ln1_b  = (const float*)d_in[4];
  const float* w_uvqk = (const float*)d_in[5];
  const float* b_uvqk = (const float*)d_in[6];
  const float* ln2_g  = (const float*)d_in[7];
  const float* ln2_b  = (const float*)d_in[8];
  const float* w_o    = (const float*)d_in[9];
  const float* b_o    = (const float*)d_in[10];
  const float* pos_w  = (const float*)d_in[11];
  const float* ts_w   = (const float*)d_in[12];
  float* out = (float*)d_out;

  float* ws = (float*)d_ws;
  const size_t SZ = (size_t)BB * NNN * DDD;            // 8M
  float* xb   = ws;                                     // 8M f
  float* buf1 = ws + SZ;                                // 8M f (o)
  ushort* ubuf = (ushort*)(ws + 2 * SZ);                // 8192x1024 bf16 (u)
  ushort* hbf = (ushort*)(ws + 3 * SZ);                 // 8M bf16
  ushort* wuT = hbf + SZ;                               // 2 x 4096x1024
  ushort* woT = wuT + 2 * (size_t)DDD * CCC;            // 2 x 1024x1024
  ushort* qkb = woT + 2 * (size_t)DDD * DDD;            // 8192x2048
  ushort* vtb = qkb + (size_t)BB * NNN * 2048;          // 64x128x1024
  ushort* rabb = vtb + (size_t)BB * HHH * DVV * NNN;    // 8x1024x1024
  float* invn = (float*)(rabb + (size_t)BB * NNN * NNN);
  float* partial = invn + (size_t)BB * NNN;
  int* lenp = (int*)(partial + (size_t)BB * 16 * DDD);

  len_k<<<BB, 1024, 0, stream>>>(mask, lenp);
  wconv_all_k<<<dim3(32, 160, 2), 256, 0, stream>>>(w_uvqk, w_o, wuT, woT);
  rab_k<<<dim3(8, 8, BB), 256, 0, stream>>>(ts, pos_w, ts_w, lenp, rabb);

  for (int l = 0; l < 2; ++l) {
    if (l == 0)
      ln_k<1><<<BB * NNN, 256, 0, stream>>>(x, ln1_g, ln1_b, nullptr,
                                            lenp, xb, hbf);
    else
      ln_k<0><<<BB * NNN, 256, 0, stream>>>(xb, ln1_g + l * DDD,
                                            ln1_b + l * DDD, nullptr,
                                            lenp, nullptr, hbf);
    gemm_bf_k<2><<<dim3(CCC / 128, BB * NNN / 128), 256, 0, stream>>>(
        hbf, wuT + (size_t)l * CCC * DDD, b_uvqk + (size_t)l * CCC,
        nullptr, ubuf, qkb, vtb, lenp, DDD, CCC);
    attn_mfma_k<<<dim3(NNN / 64, HHH, BB), 256, 0, stream>>>(
        qkb, vtb, rabb, mask, lenp, buf1);
    ln_k<0><<<BB * NNN, 256, 0, stream>>>(buf1, ln2_g + l * DDD,
                                          ln2_b + l * DDD, ubuf,
                                          lenp, nullptr, hbf);
    gemm_bf_k<1><<<dim3(DDD / 128, BB * NNN / 128), 256, 0, stream>>>(
        hbf, woT + (size_t)l * DDD * DDD, b_o + (size_t)l * DDD,
        xb, nullptr, nullptr, nullptr, lenp, DDD, DDD);
  }

  row_stats_k<<<BB * NNN, 256, 0, stream>>>(xb, lenp, invn);
  pool_partial_k<<<dim3(BB, 16), 1024, 0, stream>>>(xb, invn, lenp, partial);
  pool_final_k<<<BB, 1024, 0, stream>>>(xb, invn, partial, lenp, out);
}